// Round 5
// baseline (1092.590 us; speedup 1.0000x reference)
//
#include <hip/hip_runtime.h>

typedef __attribute__((ext_vector_type(8))) short short8;
typedef __attribute__((ext_vector_type(4))) float f32x4;

#define NT 32
#define NB 64
#define NA 16
#define NF 128
#define DT 512
#define NH 8
#define NHD 64

__device__ __forceinline__ unsigned short f2b(float f) {
  union { float f; unsigned u; } c; c.f = f;
  unsigned r = c.u + 0x7fffu + ((c.u >> 16) & 1u);
  return (unsigned short)(r >> 16);
}
__device__ __forceinline__ float b2f(unsigned short u) {
  union { unsigned u; float f; } c; c.u = ((unsigned)u) << 16;
  return c.f;
}

__device__ __forceinline__ void gload16(const void* g, void* l) {
  __builtin_amdgcn_global_load_lds(
      (const __attribute__((address_space(1))) void*)g,
      (__attribute__((address_space(3))) void*)l, 16, 0, 0);
}

#define BAR() asm volatile("s_barrier" ::: "memory")
#define WAIT_VM8() asm volatile("s_waitcnt vmcnt(8)" ::: "memory")
#define WAIT_LGKM0()                                  \
  do {                                                \
    asm volatile("s_waitcnt lgkmcnt(0)" ::: "memory");\
    __builtin_amdgcn_sched_barrier(0);                \
  } while (0)

// ---------------- f32 -> bf16 cast, 8 elems/thread ----------------
__global__ __launch_bounds__(256) void cast_kernel(const float* __restrict__ src,
                                                   unsigned short* __restrict__ dst) {
  long i = ((long)blockIdx.x * 256 + threadIdx.x) * 8;
  float4 v0 = *(const float4*)(src + i);
  float4 v1 = *(const float4*)(src + i + 4);
  uint4 o;
  o.x = f2b(v0.x) | ((unsigned)f2b(v0.y) << 16);
  o.y = f2b(v0.z) | ((unsigned)f2b(v0.w) << 16);
  o.z = f2b(v1.x) | ((unsigned)f2b(v1.y) << 16);
  o.w = f2b(v1.z) | ((unsigned)f2b(v1.w) << 16);
  *(uint4*)(dst + i) = o;
}

// =============== 256x256 fine-phase GEMM: C = A(Mx512) @ B(Nx512)^T + bias ===============
// 512 threads = 8 waves (2M x 4N); BK=32; 16 K-tiles; 4 LDS buffers (buf = T&3).
// 2 phases per tile (16 MFMA each). Per phase: ds_read (pre-barrier) | 1 half-stage
// (2 gload16) | BAR | lgkmcnt(0) | 16 MFMA | BAR. Tile U staged during tile U-3;
// uniform vmcnt(8) once per tile (4 newest stages stay in flight; awaited loads are
// >=4 phases old). Chunk-XOR swizzle (ch ^= (row>>1)&3 on 16B chunks of 64B rows),
// applied on global source (linear LDS dest) and on ds_read address (involution).
// MODE 0 = KV (NCB=2: colTiles 0,1 -> K row-linear; 2,3 -> V row-permuted)
// MODE 1 = Q  (NCB=1: bf16 row-linear)
// MODE 2 = O  (NCB=1: f32, (t,b,a)->(t,a,b) row permutation)

#define MFMA4(AF, MI)                                                                   \
  do {                                                                                  \
    acc[MI][0] = __builtin_amdgcn_mfma_f32_16x16x32_bf16(AF, b0, acc[MI][0], 0, 0, 0);  \
    acc[MI][1] = __builtin_amdgcn_mfma_f32_16x16x32_bf16(AF, b1, acc[MI][1], 0, 0, 0);  \
    acc[MI][2] = __builtin_amdgcn_mfma_f32_16x16x32_bf16(AF, b2, acc[MI][2], 0, 0, 0);  \
    acc[MI][3] = __builtin_amdgcn_mfma_f32_16x16x32_bf16(AF, b3, acc[MI][3], 0, 0, 0);  \
  } while (0)

template <int MODE, int NCB>
__global__ __launch_bounds__(512, 1) void gemm256(const unsigned short* __restrict__ A,
                                                  const unsigned short* __restrict__ Bg,
                                                  const float* __restrict__ bias0,
                                                  const float* __restrict__ bias1,
                                                  void* __restrict__ C0_,
                                                  void* __restrict__ C1_,
                                                  long row0) {
  __shared__ __align__(16) unsigned short As[4][256 * 32];
  __shared__ __align__(16) unsigned short Bs[4][256 * 32];
  const int tid = threadIdx.x;
  const int lane = tid & 63;
  const int l4 = lane & 15, lg = lane >> 4;
  const int w = tid >> 6;
  const int wm = w >> 2, wn = w & 3;

  // XCD-bijective swizzle (grid divisible by 8), colTile in low NCB bits
  const int nwg = gridDim.x;
  const int bid = blockIdx.x;
  const int swz = (bid & 7) * (nwg >> 3) + (bid >> 3);
  const long rowTile = swz >> NCB;
  const int colTile = swz & ((1 << NCB) - 1);

  // staging: thread tid covers LDS bytes tid*16 (row tid>>2, 16B-chunk tid&3 of [256][32])
  // plus +8KB (row+128). Source chunk pre-swizzled: ch ^ ((row>>1)&3) (row bits identical
  // for both rounds, so one per-thread source offset works for both).
  const int sch = (tid & 3) ^ ((tid >> 3) & 3);
  const unsigned short* Agl = A + (rowTile * 256 + (tid >> 2)) * 512L + sch * 8;
  const unsigned short* Bgl = Bg + ((long)colTile * 256 + (tid >> 2)) * 512L + sch * 8;

  auto stgA = [&](int buf, int kb) {
    gload16(Agl + kb, &As[buf][w * 512]);
    gload16(Agl + kb + 128 * 512L, &As[buf][4096 + w * 512]);
  };
  auto stgB = [&](int buf, int kb) {
    gload16(Bgl + kb, &Bs[buf][w * 512]);
    gload16(Bgl + kb + 128 * 512L, &Bs[buf][4096 + w * 512]);
  };

  // frag-read column offset (elems) within a row — phase-invariant ((rr>>1)&3 == (l4>>1)&3)
  const int kcol = ((lg ^ ((l4 >> 1) & 3)) << 3);
  const int aRow = wm * 128 + l4;
  const int bRow = wn * 64 + l4;

  const f32x4 zero = {0.f, 0.f, 0.f, 0.f};
  f32x4 acc[8][4];
#pragma unroll
  for (int i = 0; i < 8; i++)
#pragma unroll
    for (int j = 0; j < 4; j++) acc[i][j] = zero;

  // prologue: tiles 0,1,2 staged; vmcnt(8) confirms tile 0 (leaves tiles 1,2 in flight)
  stgA(0, 0);
  stgB(0, 0);
  stgA(1, 32);
  stgB(1, 32);
  stgA(2, 64);
  stgB(2, 64);
  WAIT_VM8();
  BAR();

#pragma unroll 1
  for (int T = 0; T < 16; T++) {
    const int buf = T & 3;
    const int U = T + 3;
    const int kb = (U < 16 ? U : 15) * 32;  // clamped dummy stages keep vmcnt ledger uniform
    const int ub = U & 3;
    const unsigned short* Ab = &As[buf][kcol];
    const unsigned short* Bb = &Bs[buf][kcol];
    // ---- phase A: reads issued pre-barrier (hide under other waves' prior MFMA) ----
    short8 b0 = *(const short8*)&Bb[(bRow + 0) * 32];
    short8 b1 = *(const short8*)&Bb[(bRow + 16) * 32];
    short8 b2 = *(const short8*)&Bb[(bRow + 32) * 32];
    short8 b3 = *(const short8*)&Bb[(bRow + 48) * 32];
    short8 a0 = *(const short8*)&Ab[(aRow + 0) * 32];
    short8 a1 = *(const short8*)&Ab[(aRow + 16) * 32];
    short8 a2 = *(const short8*)&Ab[(aRow + 32) * 32];
    short8 a3 = *(const short8*)&Ab[(aRow + 48) * 32];
    stgA(ub, kb);
    BAR();
    WAIT_LGKM0();
    __builtin_amdgcn_s_setprio(1);
    MFMA4(a0, 0);
    MFMA4(a1, 1);
    MFMA4(a2, 2);
    MFMA4(a3, 3);
    __builtin_amdgcn_s_setprio(0);
    BAR();
    // ---- phase B: 4 A-frags (B reused in regs); vmcnt(8) confirms tile T+1 ----
    short8 a4 = *(const short8*)&Ab[(aRow + 64) * 32];
    short8 a5 = *(const short8*)&Ab[(aRow + 80) * 32];
    short8 a6 = *(const short8*)&Ab[(aRow + 96) * 32];
    short8 a7 = *(const short8*)&Ab[(aRow + 112) * 32];
    stgB(ub, kb);
    WAIT_VM8();
    BAR();
    WAIT_LGKM0();
    __builtin_amdgcn_s_setprio(1);
    MFMA4(a4, 4);
    MFMA4(a5, 5);
    MFMA4(a6, 6);
    MFMA4(a7, 7);
    __builtin_amdgcn_s_setprio(0);
    BAR();
  }
  asm volatile("s_waitcnt vmcnt(0)" ::: "memory");  // drain dummy stages before endpgm

  const long gRowBase = row0 + rowTile * 256 + wm * 128;

  if constexpr (MODE == 0) {  // KV
    if (colTile < 2) {        // K side: row-linear
      unsigned short* C = (unsigned short*)C0_;
#pragma unroll
      for (int n = 0; n < 4; n++) {
        int gCol = colTile * 256 + wn * 64 + n * 16 + l4;
        float bs = bias0[gCol];
#pragma unroll
        for (int m = 0; m < 8; m++)
#pragma unroll
          for (int r = 0; r < 4; r++) {
            long gRow = gRowBase + m * 16 + lg * 4 + r;
            C[gRow * 512 + gCol] = f2b(acc[m][n][r] + bs);
          }
      }
    } else {  // V side: row (fi*64+bi) -> (bi*128+fi) within each t
      unsigned short* C = (unsigned short*)C1_;
#pragma unroll
      for (int n = 0; n < 4; n++) {
        int gCol = (colTile - 2) * 256 + wn * 64 + n * 16 + l4;
        float bs = bias1[gCol];
#pragma unroll
        for (int m = 0; m < 8; m++)
#pragma unroll
          for (int r = 0; r < 4; r++) {
            long gRow = gRowBase + m * 16 + lg * 4 + r;
            long rr = gRow & 8191;
            long vrow = (gRow - rr) + ((rr & 63) << 7) + (rr >> 6);
            C[vrow * 512 + gCol] = f2b(acc[m][n][r] + bs);
          }
      }
    }
  } else if constexpr (MODE == 1) {  // Q: bf16 row-linear
    unsigned short* C = (unsigned short*)C0_;
#pragma unroll
    for (int n = 0; n < 4; n++) {
      int gCol = colTile * 256 + wn * 64 + n * 16 + l4;
      float bs = bias0[gCol];
#pragma unroll
      for (int m = 0; m < 8; m++)
#pragma unroll
        for (int r = 0; r < 4; r++) {
          long gRow = gRowBase + m * 16 + lg * 4 + r;
          C[gRow * 512 + gCol] = f2b(acc[m][n][r] + bs);
        }
    }
  } else {  // O: f32, rows (t*64+b)*16+a -> out row (t*16+a)*64+b
    float* C = (float*)C0_;
#pragma unroll
    for (int n = 0; n < 4; n++) {
      int gCol = colTile * 256 + wn * 64 + n * 16 + l4;
      float bs = bias0[gCol];
#pragma unroll
      for (int m = 0; m < 8; m++)
#pragma unroll
        for (int r = 0; r < 4; r++) {
          long gRow = gRowBase + m * 16 + lg * 4 + r;
          long tt = gRow >> 10;
          long bi = (gRow >> 4) & 63;
          long ai = gRow & 15;
          long orow = ((tt * 16 + ai) << 6) + bi;
          C[orow * 512 + gCol] = acc[m][n][r] + bs;
        }
    }
  }
}

// ---------------- attention: one block per (t,b); 4 waves x 2 heads ----------------
__global__ __launch_bounds__(256, 2) void attn_kernel(const unsigned short* __restrict__ Kst,
                                                      const unsigned short* __restrict__ Vst,
                                                      const unsigned short* __restrict__ Qst,
                                                      const int* __restrict__ mask,
                                                      float* __restrict__ wout,
                                                      unsigned short* __restrict__ attn_out) {
  __shared__ float wsh[4][NF * NA];
  __shared__ int msh[NF];
  const int tid = threadIdx.x;
  const int lane = tid & 63;
  const int l4 = lane & 15, lg = lane >> 4;
  const int w = tid >> 6;
  const int tb = blockIdx.x;
  const int b = tb & 63;
  if (tid < NF) msh[tid] = mask[b * NF + tid];
  __syncthreads();

  const unsigned short* Kbase = Kst + (long)tb * NF * DT;
  const unsigned short* Vbase = Vst + (long)tb * NF * DT;
  const unsigned short* Qbase = Qst + (long)tb * NA * DT;
  const f32x4 zero = {0.f, 0.f, 0.f, 0.f};

  for (int hh = 0; hh < 2; hh++) {
    const int h = w * 2 + hh;
    const int co = h * 64;
    f32x4 acc[8];
#pragma unroll
    for (int i = 0; i < 8; i++) acc[i] = zero;
#pragma unroll
    for (int ks = 0; ks < 2; ks++) {
      short8 qf = *(const short8*)(Qbase + (long)l4 * DT + co + ks * 32 + lg * 8);
#pragma unroll
      for (int m0 = 0; m0 < 8; m0++) {
        short8 kf = *(const short8*)(Kbase + (long)(m0 * 16 + l4) * DT + co + ks * 32 + lg * 8);
        acc[m0] = __builtin_amdgcn_mfma_f32_16x16x32_bf16(kf, qf, acc[m0], 0, 0, 0);
      }
    }
    float lv[8][4];
    float mx = -3.0e38f;
#pragma unroll
    for (int m0 = 0; m0 < 8; m0++)
#pragma unroll
      for (int r = 0; r < 4; r++) {
        int f = m0 * 16 + lg * 4 + r;
        float v = acc[m0][r] * 0.125f;
        if (msh[f] == 0) v = -1.0e9f;
        lv[m0][r] = v;
        mx = fmaxf(mx, v);
      }
    mx = fmaxf(mx, __shfl_xor(mx, 16, 64));
    mx = fmaxf(mx, __shfl_xor(mx, 32, 64));
    float s = 0.f;
#pragma unroll
    for (int m0 = 0; m0 < 8; m0++)
#pragma unroll
      for (int r = 0; r < 4; r++) {
        float p = __expf(lv[m0][r] - mx);
        lv[m0][r] = p;
        s += p;
      }
    s += __shfl_xor(s, 16, 64);
    s += __shfl_xor(s, 32, 64);
    float inv = 1.0f / s;
    float* wrow = wout + ((long)tb * NH + h) * (NF * NA);
#pragma unroll
    for (int m0 = 0; m0 < 8; m0++)
#pragma unroll
      for (int r = 0; r < 4; r++) {
        int f = m0 * 16 + lg * 4 + r;
        float wv = lv[m0][r] * inv;
        wsh[w][f * 16 + l4] = wv;
        wrow[f * 16 + l4] = wv;
      }
    float pv[16];
#pragma unroll
    for (int a = 0; a < 16; a++) pv[a] = 0.f;
#pragma unroll 4
    for (int f = 0; f < NF; f++) {
      float vv = b2f(Vbase[(long)f * DT + co + lane]);
      const float4* wp = (const float4*)&wsh[w][f * 16];
      float4 w0 = wp[0], w1 = wp[1], w2 = wp[2], w3 = wp[3];
      pv[0] += vv * w0.x;  pv[1] += vv * w0.y;  pv[2] += vv * w0.z;  pv[3] += vv * w0.w;
      pv[4] += vv * w1.x;  pv[5] += vv * w1.y;  pv[6] += vv * w1.z;  pv[7] += vv * w1.w;
      pv[8] += vv * w2.x;  pv[9] += vv * w2.y;  pv[10] += vv * w2.z; pv[11] += vv * w2.w;
      pv[12] += vv * w3.x; pv[13] += vv * w3.y; pv[14] += vv * w3.z; pv[15] += vv * w3.w;
    }
#pragma unroll
    for (int a = 0; a < 16; a++)
      attn_out[((long)tb * NA + a) * DT + co + lane] = f2b(pv[a]);
  }
}

extern "C" void kernel_launch(void* const* d_in, const int* in_sizes, int n_in,
                              void* d_out, int out_size, void* d_ws, size_t ws_size,
                              hipStream_t stream) {
  const float* q_embeds = (const float*)d_in[0];
  const float* ctx = (const float*)d_in[1];
  const int* mask = (const int*)d_in[2];
  const float* Wq = (const float*)d_in[3];
  const float* bq = (const float*)d_in[4];
  const float* Wk = (const float*)d_in[5];
  const float* bk = (const float*)d_in[6];
  const float* Wv = (const float*)d_in[7];
  const float* bv = (const float*)d_in[8];
  const float* Wo = (const float*)d_in[9];
  const float* bo = (const float*)d_in[10];

  float* out0 = (float*)d_out;                   // (t,a,b,d) f32
  float* wout = out0 + (long)NT * NA * NB * DT;  // (t,b,H,f,a) f32

  const long W_ELEMS = 4L * 512 * 512;
  const long MQ = (long)NT * NB * NA;    // 32768
  const long MKV = (long)NT * NF * NB;   // 262144
  const long CHUNK_ROWS = MKV / 8;       // 32768
  unsigned short* Wb = (unsigned short*)d_ws;
  unsigned short* Qst = Wb + W_ELEMS;
  unsigned short* Kst = Qst + MQ * DT;
  unsigned short* Vst = Kst + MKV * DT;
  unsigned short* ctxb = Vst + MKV * DT;   // scratch: q bf16, then ctx bf16, then attnst
  unsigned short* attnst = ctxb;           // alias: ctxb dead before attn runs

  const size_t needed_chunk = (size_t)(W_ELEMS + MQ * DT + 2 * MKV * DT + CHUNK_ROWS * DT) * 2;
  const size_t needed_full = (size_t)(W_ELEMS + MQ * DT + 3 * MKV * DT) * 2;
  if (ws_size < needed_chunk) return;
  const bool fullpass = ws_size >= needed_full;

  cast_kernel<<<128, 256, 0, stream>>>(Wq, Wb);
  cast_kernel<<<128, 256, 0, stream>>>(Wk, Wb + 512 * 512);
  cast_kernel<<<128, 256, 0, stream>>>(Wv, Wb + 2 * 512 * 512);
  cast_kernel<<<128, 256, 0, stream>>>(Wo, Wb + 3 * 512 * 512);

  // Q projection: cast A to bf16 (into ctxb scratch), then 256^2 GEMM
  cast_kernel<<<(unsigned)(MQ * DT / 2048), 256, 0, stream>>>(q_embeds, ctxb);
  gemm256<1, 1><<<(unsigned)(MQ / 256 * 2), 512, 0, stream>>>(ctxb, Wb, bq, nullptr, Qst,
                                                              nullptr, 0);

  if (fullpass) {
    cast_kernel<<<(unsigned)(MKV * DT / 2048), 256, 0, stream>>>(ctx, ctxb);
    gemm256<0, 2><<<(unsigned)(MKV / 256 * 4), 512, 0, stream>>>(ctxb, Wb + 512 * 512, bk, bv,
                                                                 Kst, Vst, 0);
  } else {
    for (int c = 0; c < 8; c++) {
      cast_kernel<<<(unsigned)(CHUNK_ROWS * DT / 2048), 256, 0, stream>>>(
          ctx + (long)c * CHUNK_ROWS * DT, ctxb);
      gemm256<0, 2><<<(unsigned)(CHUNK_ROWS / 256 * 4), 512, 0, stream>>>(
          ctxb, Wb + 512 * 512, bk, bv, Kst, Vst, (long)c * CHUNK_ROWS);
    }
  }

  attn_kernel<<<NT * NB, 256, 0, stream>>>(Kst, Vst, Qst, mask, wout, attnst);

  gemm256<2, 1><<<(unsigned)(MQ / 256 * 2), 512, 0, stream>>>(attnst, Wb + 3 * 512 * 512, bo,
                                                              nullptr, out0, nullptr, 0);
}